// Round 10
// baseline (163.836 us; speedup 1.0000x reference)
//
#include <hip/hip_runtime.h>
#include <hip/hip_bf16.h>
#include <stdint.h>

// VQ-VAE vector quantizer for MI355X (gfx950)
// z: [32768,256] f32, codebook: [256,8192] f32
// out: z_q [8388608] f32, indices-as-f32 [32768], loss [1]
//
// Round 10: round-9 i8 MFMA scan re-tiled for 2 blocks/CU (m114 de-sync):
// 64-row blocks, 256 threads (4 waves = 4 code groups), LDS = z 16KB +
// B 2x32KB double buffer = 80KB. Loads issued AFTER the step barrier ->
// double buffer race-free; vmcnt(0) waits loads issued a full step earlier.
// Two independent blocks per CU overlap fold-VALU with the other block's
// MFMA. Score math, key packing, 64-bucket top-2 cand layout, fp64 top-5
// refine all byte-identical to passing round 9.

#define DEVINL __device__ __forceinline__

typedef int   intx4 __attribute__((ext_vector_type(4)));

#define NROWS   32768
#define DIMS    256
#define NCODES  8192
#define KMIN    ((int)0x80000000)

// ---------------- helpers ----------------
DEVINL int q8(float v, float s) {
  int q = __float2int_rn(v * s);
  return min(127, max(-127, q));
}
DEVINL unsigned pk4(float4 v, float s) {
  int a = q8(v.x, s), b = q8(v.y, s), c = q8(v.z, s), d = q8(v.w, s);
  return (unsigned)(a & 255) | ((unsigned)(b & 255) << 8) |
         ((unsigned)(c & 255) << 16) | ((unsigned)(d & 255) << 24);
}
DEVINL void gload_lds16(const void* g, void* lds) {
  __builtin_amdgcn_global_load_lds(
      (const __attribute__((address_space(1))) uint32_t*)(uintptr_t)g,
      (__attribute__((address_space(3))) uint32_t*)(uint32_t)(uintptr_t)lds,
      16, 0, 0);
}

// ---------------- K1: scaled norms of quantized codes ----------------
// nrm[j] = rint( (25/254) * sum_d q8(c[d][j]*127)^2 )
//   so (dot - nrm) == 3175 * (z.c - ||c||^2/2) in quantized units.
__global__ void k_nrm(const float* __restrict__ cb, int* __restrict__ nrm) {
  __shared__ int p[256];
  int j = blockIdx.x * 32 + (threadIdx.x & 31);
  int seg = threadIdx.x >> 5;
  int s = 0;
  for (int i = 0; i < 32; ++i) {
    int q = q8(cb[(size_t)(seg * 32 + i) * NCODES + j], 127.0f);
    s += q * q;
  }
  p[threadIdx.x] = s;
  __syncthreads();
  if (threadIdx.x < 32) {
    int t = 0;
    for (int k = 0; k < 8; ++k) t += p[k * 32 + threadIdx.x];
    nrm[j] = (int)rintf((25.0f / 254.0f) * (float)t);
  }
}

// ---------------- K2: f32 transpose cbTf[j][d] (for exact refine) ----------
__global__ void k_transpose(const float* __restrict__ cb, float* __restrict__ cbTf) {
  __shared__ float t[64][65];
  int j0 = blockIdx.x * 64, d0 = blockIdx.y * 64;
  int tx = threadIdx.x & 63, ty = threadIdx.x >> 6;
  #pragma unroll
  for (int i = 0; i < 16; ++i) {
    int dl = i * 4 + ty;
    t[dl][tx] = cb[(size_t)(d0 + dl) * NCODES + j0 + tx];
  }
  __syncthreads();
  #pragma unroll
  for (int i = 0; i < 16; ++i) {
    int jl = i * 4 + ty;
    cbTf[(size_t)(j0 + jl) * DIMS + d0 + tx] = t[tx][jl];
  }
}

// ---------------- K3: i8 fragment image ----------------
// granule g (16B = 16 K-bytes) = [step 64][wc 4][cf 8][lgr 4][l15 16]
//   step = tile*4+chunk; code j = tile*512 + wc*128 + cf*16 + l15
//   dims d = chunk*64 + lgr*16 .. +16  (linear K within granule)
__global__ void k_image(const float* __restrict__ cbTf, uint4* __restrict__ img) {
  int g = blockIdx.x * 256 + threadIdx.x;     // 0..131071
  int step = g >> 11;                          // 0..63
  int r = g & 2047;
  int wc = r >> 9, cf = (r >> 6) & 7, lgr = (r >> 4) & 3, l15 = r & 15;
  int tile = step >> 2, chunk = step & 3;
  int j = tile * 512 + wc * 128 + cf * 16 + l15;
  int d = chunk * 64 + lgr * 16;
  const float4* s4 = (const float4*)(cbTf + (size_t)j * DIMS + d);
  uint4 o;
  o.x = pk4(s4[0], 127.0f); o.y = pk4(s4[1], 127.0f);
  o.z = pk4(s4[2], 127.0f); o.w = pk4(s4[3], 127.0f);
  img[g] = o;
}

// ---------------- K4: i8 MFMA scan, 2 blocks/CU double buffer --------------
// 512 blocks x 256 threads. Block: 64 rows x 8192 codes, 64 steps of K=64.
// 4 waves = 4 code groups; wave-tile 64 rows x 128 codes; 16x16x64 rf4 x cf8.
// LDS: z 16KB (i8 swizzled) | B 2x32KB = 80KB -> 2 blocks/CU.
// Step s: vmcnt(0)+barrier (waits loads issued at s-1, a full step earlier);
// issue step s+1 into buf[(s+1)&1] (safe: all waves done reading it at s-1);
// compute from buf[s&1].
__global__ __launch_bounds__(256, 2)
void k_scan(const float* __restrict__ z, const int* __restrict__ nrm,
            const uint4* __restrict__ img, int2* __restrict__ cand) {
  __shared__ char smem[81920];
  char* const zb = smem;                        // 16 KB: 64 rows x 256 i8
  char* const bb = smem + 16384;                // 2 x 32 KB B buffers

  const int t = threadIdx.x;
  const int lane = t & 63;
  const int wave = t >> 6;                      // code group 0..3
  const int l15 = lane & 15;
  const int lgr = lane >> 4;
  const int brow = blockIdx.x * 64;

  // stage z: 1024 granules (16 K-bytes each); pos = (kblk*16)^((row&15)<<4)
  #pragma unroll
  for (int i = 0; i < 4; ++i) {
    int g = t + i * 256;
    int row = g >> 4, kb = g & 15;
    const float4* src = (const float4*)(z + (size_t)(brow + row) * DIMS + kb * 16);
    uint4 o;
    o.x = pk4(src[0], 25.0f); o.y = pk4(src[1], 25.0f);
    o.z = pk4(src[2], 25.0f); o.w = pk4(src[3], 25.0f);
    int addr = row * 256 + ((kb * 16) ^ ((row & 15) << 4));
    *(uint4*)(zb + addr) = o;
  }
  // stage B step 0 into buf0: 8 granules/thread (wave-uniform base + lane*16)
  {
    const uint4* gsrc = img + wave * 64 + lane;
    #pragma unroll
    for (int i = 0; i < 8; ++i)
      gload_lds16(gsrc + i * 256, bb + (i * 256 + wave * 64) * 16);
  }

  // per row-slot top-2 packed keys
  int k1[16], k2[16];
  #pragma unroll
  for (int i = 0; i < 16; ++i) { k1[i] = KMIN; k2[i] = KMIN; }

  __syncthreads();   // z visible; step-0 B resident (vmcnt(0)+lgkm drain)

  intx4 acc[4][8];

  #pragma unroll 1
  for (int s = 0; s < 64; ++s) {
    const int tile = s >> 2, chunk = s & 3;

    if (s > 0) {
      asm volatile("s_waitcnt vmcnt(0)" ::: "memory");  // step-s loads landed
      __builtin_amdgcn_s_barrier();
    }
    if (s < 63) {
      // issue next step AFTER the barrier: buf[(s+1)&1] free of readers
      const uint4* gsrc = img + (size_t)(s + 1) * 2048 + wave * 64 + lane;
      char* dst = bb + ((s + 1) & 1) * 32768;
      #pragma unroll
      for (int i = 0; i < 8; ++i)
        gload_lds16(gsrc + i * 256, dst + (i * 256 + wave * 64) * 16);
    }

    const char* cbuf = bb + (s & 1) * 32768;

    // acc init: -nrm (scaled norm), nrm is L1/L2-resident
    if (chunk == 0) {
      #pragma unroll
      for (int cf = 0; cf < 8; ++cf) {
        int h = -nrm[tile * 512 + wave * 128 + cf * 16 + l15];
        #pragma unroll
        for (int rf = 0; rf < 4; ++rf) acc[rf][cf] = intx4{h, h, h, h};
      }
    }

    // fragments
    intx4 a[4], b[8];
    #pragma unroll
    for (int rf = 0; rf < 4; ++rf) {
      int m = rf * 16 + l15;
      int by = (chunk * 64 + lgr * 16) ^ (l15 << 4);
      a[rf] = *(const intx4*)(zb + m * 256 + by);
    }
    #pragma unroll
    for (int cf = 0; cf < 8; ++cf)
      b[cf] = *(const intx4*)(cbuf + (wave * 512 + cf * 64 + lane) * 16);

    #pragma unroll
    for (int rf = 0; rf < 4; ++rf)
      #pragma unroll
      for (int cf = 0; cf < 8; ++cf)
        acc[rf][cf] = __builtin_amdgcn_mfma_i32_16x16x64_i8(a[rf], b[cf], acc[rf][cf], 0, 0, 0);

    // tile epilogue: fold 8 int scores/row-slot into running top-2
    if (chunk == 3) {
      const int jinvb = 8191 - (tile * 512 + wave * 128 + l15);
      #pragma unroll
      for (int rf = 0; rf < 4; ++rf)
        #pragma unroll
        for (int cf = 0; cf < 8; ++cf) {
          int jinv = jinvb - cf * 16;
          #pragma unroll
          for (int r = 0; r < 4; ++r) {
            int si = rf * 4 + r;
            int k = ((acc[rf][cf][r] >> 5) << 13) + jinv;
            int t1 = max(k1[si], k);
            int t2 = min(k1[si], k);
            k1[si] = t1;
            k2[si] = max(k2[si], t2);
          }
        }
    }
  }

  // write candidates: [row][64 buckets] int2
  #pragma unroll
  for (int rf = 0; rf < 4; ++rf)
    #pragma unroll
    for (int r = 0; r < 4; ++r) {
      int row = brow + rf * 16 + lgr * 4 + r;
      int si = rf * 4 + r;
      cand[(size_t)row * 64 + wave * 16 + l15] = make_int2(k1[si], k2[si]);
    }
}

// ---------------- K5: exact fp64 refine (top-5) + outputs + loss partials ----
__global__ __launch_bounds__(512)
void k_refine(const float* __restrict__ z, const float* __restrict__ cbTf,
              const int2* __restrict__ cand, float* __restrict__ zq,
              float* __restrict__ oidx, double* __restrict__ parts) {
  __shared__ double lsum[8];
  int lane = threadIdx.x & 63, wave = threadIdx.x >> 6;
  int row = blockIdx.x * 8 + wave;

  float4 z4 = ((const float4*)(z + (size_t)row * DIMS))[lane];
  int2 kp = cand[(size_t)row * 64 + lane];
  int ka = kp.x, kb = kp.y;

  double bd = 1e300; int bj = -1; float4 bc = {0.f, 0.f, 0.f, 0.f};
  for (int s = 0; s < 5; ++s) {
    int km = max(ka, kb);
    #pragma unroll
    for (int m = 1; m < 64; m <<= 1) km = max(km, __shfl_xor(km, m, 64));
    int j = 8191 - (km & 8191);
    if (ka == km) ka = KMIN; else if (kb == km) kb = KMIN;

    float4 c4 = ((const float4*)(cbTf + (size_t)j * DIMS))[lane];
    double dx = (double)z4.x - (double)c4.x;
    double dy = (double)z4.y - (double)c4.y;
    double dzv = (double)z4.z - (double)c4.z;
    double dw = (double)z4.w - (double)c4.w;
    double d = dx * dx + dy * dy + dzv * dzv + dw * dw;
    #pragma unroll
    for (int m = 1; m < 64; m <<= 1) d += __shfl_xor(d, m, 64);

    bool bt = (d < bd) || (d == bd && j < bj);   // wave-uniform
    if (bt) { bd = d; bj = j; bc = c4; }
  }

  ((float4*)(zq + (size_t)row * DIMS))[lane] = bc;
  if (lane == 0) oidx[row] = (float)bj;

  double lx = (double)bc.x - (double)z4.x;
  double ly = (double)bc.y - (double)z4.y;
  double lz = (double)bc.z - (double)z4.z;
  double lw = (double)bc.w - (double)z4.w;
  double l = lx * lx + ly * ly + lz * lz + lw * lw;
  #pragma unroll
  for (int m = 1; m < 64; m <<= 1) l += __shfl_xor(l, m, 64);
  if (lane == 0) lsum[wave] = l;
  __syncthreads();
  if (threadIdx.x == 0) {
    double s = 0;
    for (int i = 0; i < 8; ++i) s += lsum[i];
    parts[blockIdx.x] = s;
  }
}

// ---------------- K6: loss finalize ----------------
__global__ void k_finish(const double* __restrict__ parts, float* __restrict__ out) {
  __shared__ double s[256];
  double a = 0;
  for (int i = threadIdx.x; i < 4096; i += 256) a += parts[i];
  s[threadIdx.x] = a;
  __syncthreads();
  for (int w = 128; w; w >>= 1) {
    if (threadIdx.x < w) s[threadIdx.x] += s[threadIdx.x + w];
    __syncthreads();
  }
  if (threadIdx.x == 0) out[0] = (float)(1.25 * s[0] / 8388608.0);
}

// ---------------- launch ----------------
extern "C" void kernel_launch(void* const* d_in, const int* in_sizes, int n_in,
                              void* d_out, int out_size, void* d_ws, size_t ws_size,
                              hipStream_t stream) {
  const float* zin = (const float*)d_in[0];
  const float* cb  = (const float*)d_in[1];
  float* out = (float*)d_out;

  char* w = (char*)d_ws;
  int*    nrm   = (int*)w;                                          // 32 KB
  float*  cbTf  = (float*)(w + 32768);                              // 8 MB
  char*   imgb  = w + 32768 + 8388608;                              // 2 MB
  int2*   cand  = (int2*)(w + 32768 + 8388608 + 2097152);           // 16 MB
  double* parts = (double*)(w + 32768 + 8388608 + 2097152 + 16777216); // 32 KB

  float* zq_out   = out;
  float* idx_out  = out + 8388608;
  float* loss_out = out + 8388608 + 32768;

  k_nrm<<<dim3(256), dim3(256), 0, stream>>>(cb, nrm);
  k_transpose<<<dim3(128, 4), dim3(256), 0, stream>>>(cb, cbTf);
  k_image<<<dim3(512), dim3(256), 0, stream>>>(cbTf, (uint4*)imgb);
  k_scan<<<dim3(512), dim3(256), 0, stream>>>(zin, nrm, (const uint4*)imgb, cand);
  k_refine<<<dim3(4096), dim3(512), 0, stream>>>(zin, cbTf, cand, zq_out, idx_out, parts);
  k_finish<<<dim3(1), dim3(256), 0, stream>>>(parts, loss_out);
}

// Round 11
// 162.624 us; speedup vs baseline: 1.0075x; 1.0075x over previous
//
#include <hip/hip_runtime.h>
#include <hip/hip_bf16.h>
#include <stdint.h>

// VQ-VAE vector quantizer for MI355X (gfx950)
// z: [32768,256] f32, codebook: [256,8192] f32
// out: z_q [8388608] f32, indices-as-f32 [32768], loss [1]
//
// Round 11: round-9 base (128-row blocks, 512 thr, 8 waves, i8 MFMA
// 16x16x64), with (a) 2-step staging windows: 2x64KB double-buffered B,
// ONE barrier per 2 chunks (32 sync events instead of 64), nrm from global;
// (b) med3-based top-2 insertion (4 VALU ops/score-exam instead of 6:
// k1'=max(k1,k), k2'=v_med3_i32(k,k1,k2) — equal to max/min/max under the
// k1>=k2 invariant). Score math, key packing, bucket partition, cand layout,
// fp64 top-5 refine bit-identical to passing rounds 9/10.

#define DEVINL __device__ __forceinline__

typedef int   intx4 __attribute__((ext_vector_type(4)));

#define NROWS   32768
#define DIMS    256
#define NCODES  8192
#define KMIN    ((int)0x80000000)

// ---------------- helpers ----------------
DEVINL int q8(float v, float s) {
  int q = __float2int_rn(v * s);
  return min(127, max(-127, q));
}
DEVINL unsigned pk4(float4 v, float s) {
  int a = q8(v.x, s), b = q8(v.y, s), c = q8(v.z, s), d = q8(v.w, s);
  return (unsigned)(a & 255) | ((unsigned)(b & 255) << 8) |
         ((unsigned)(c & 255) << 16) | ((unsigned)(d & 255) << 24);
}
DEVINL void gload_lds16(const void* g, void* lds) {
  __builtin_amdgcn_global_load_lds(
      (const __attribute__((address_space(1))) uint32_t*)(uintptr_t)g,
      (__attribute__((address_space(3))) uint32_t*)(uint32_t)(uintptr_t)lds,
      16, 0, 0);
}

// ---------------- K1: scaled norms of quantized codes ----------------
// nrm[j] = rint( (25/254) * sum_d q8(c[d][j]*127)^2 )
//   so (dot - nrm) == 3175 * (z.c - ||c||^2/2) in quantized units.
__global__ void k_nrm(const float* __restrict__ cb, int* __restrict__ nrm) {
  __shared__ int p[256];
  int j = blockIdx.x * 32 + (threadIdx.x & 31);
  int seg = threadIdx.x >> 5;
  int s = 0;
  for (int i = 0; i < 32; ++i) {
    int q = q8(cb[(size_t)(seg * 32 + i) * NCODES + j], 127.0f);
    s += q * q;
  }
  p[threadIdx.x] = s;
  __syncthreads();
  if (threadIdx.x < 32) {
    int t = 0;
    for (int k = 0; k < 8; ++k) t += p[k * 32 + threadIdx.x];
    nrm[j] = (int)rintf((25.0f / 254.0f) * (float)t);
  }
}

// ---------------- K2: f32 transpose cbTf[j][d] (for exact refine) ----------
__global__ void k_transpose(const float* __restrict__ cb, float* __restrict__ cbTf) {
  __shared__ float t[64][65];
  int j0 = blockIdx.x * 64, d0 = blockIdx.y * 64;
  int tx = threadIdx.x & 63, ty = threadIdx.x >> 6;
  #pragma unroll
  for (int i = 0; i < 16; ++i) {
    int dl = i * 4 + ty;
    t[dl][tx] = cb[(size_t)(d0 + dl) * NCODES + j0 + tx];
  }
  __syncthreads();
  #pragma unroll
  for (int i = 0; i < 16; ++i) {
    int jl = i * 4 + ty;
    cbTf[(size_t)(j0 + jl) * DIMS + d0 + tx] = t[tx][jl];
  }
}

// ---------------- K3: i8 fragment image ----------------
// granule g (16B = 16 K-bytes) = [step 64][wc 4][cf 8][lgr 4][l15 16]
//   step = tile*4+chunk; code j = tile*512 + wc*128 + cf*16 + l15
//   dims d = chunk*64 + lgr*16 .. +16  (linear K within granule)
__global__ void k_image(const float* __restrict__ cbTf, uint4* __restrict__ img) {
  int g = blockIdx.x * 256 + threadIdx.x;     // 0..131071
  int step = g >> 11;                          // 0..63
  int r = g & 2047;
  int wc = r >> 9, cf = (r >> 6) & 7, lgr = (r >> 4) & 3, l15 = r & 15;
  int tile = step >> 2, chunk = step & 3;
  int j = tile * 512 + wc * 128 + cf * 16 + l15;
  int d = chunk * 64 + lgr * 16;
  const float4* s4 = (const float4*)(cbTf + (size_t)j * DIMS + d);
  uint4 o;
  o.x = pk4(s4[0], 127.0f); o.y = pk4(s4[1], 127.0f);
  o.z = pk4(s4[2], 127.0f); o.w = pk4(s4[3], 127.0f);
  img[g] = o;
}

// ---------------- K4: i8 MFMA scan, 2-step windows, med3 fold --------------
// 256 blocks x 512 threads. Block: 128 rows x 8192 codes.
// 32 windows of 2 chunks (K=128 staged per window, 64KB).
// Waves: wgr(2) x wc(4); wave-tile 64 rows x 128 codes; 16x16x64 rf4 x cf8.
// LDS: z 32KB (i8 swizzled) | B 2x64KB double buffer = 160KB.
// Window w: vmcnt(0)+barrier; issue w+1 loads (into the buffer whose readers
// finished at this barrier); compute 2 chunks from buf[w&1]; fold on odd w.
__global__ __launch_bounds__(512, 2)
void k_scan(const float* __restrict__ z, const int* __restrict__ nrm,
            const uint4* __restrict__ img, int2* __restrict__ cand) {
  __shared__ char smem[163840];
  char* const zb = smem;                        // 32 KB: 128 rows x 256 i8
  char* const bb = smem + 32768;                // 2 x 64 KB B windows

  const int t = threadIdx.x;
  const int lane = t & 63;
  const int wave = t >> 6;
  const int wgr = wave >> 2;
  const int wc  = wave & 3;
  const int l15 = lane & 15;
  const int lgr = lane >> 4;
  const int brow = blockIdx.x * 128;

  // stage z: 2048 granules (16 K-bytes each); pos = (kblk*16)^((row&15)<<4)
  #pragma unroll
  for (int i = 0; i < 4; ++i) {
    int g = t + i * 512;
    int row = g >> 4, kb = g & 15;
    const float4* src = (const float4*)(z + (size_t)(brow + row) * DIMS + kb * 16);
    uint4 o;
    o.x = pk4(src[0], 25.0f); o.y = pk4(src[1], 25.0f);
    o.z = pk4(src[2], 25.0f); o.w = pk4(src[3], 25.0f);
    int addr = row * 256 + ((kb * 16) ^ ((row & 15) << 4));
    *(uint4*)(zb + addr) = o;
  }
  // stage B window 0 (4096 granules) into buf0: 8 per thread
  {
    const uint4* gsrc = img + wave * 64 + lane;
    #pragma unroll
    for (int i = 0; i < 8; ++i)
      gload_lds16(gsrc + i * 512, bb + (i * 512 + wave * 64) * 16);
  }

  // per row-slot top-2 packed keys
  int k1[16], k2[16];
  #pragma unroll
  for (int i = 0; i < 16; ++i) { k1[i] = KMIN; k2[i] = KMIN; }

  __syncthreads();   // z visible; window-0 B resident

  intx4 acc[4][8];

  #pragma unroll 1
  for (int w = 0; w < 32; ++w) {
    const int tile = w >> 1;

    if (w > 0) {
      asm volatile("s_waitcnt vmcnt(0)" ::: "memory");  // window-w loads landed
      __builtin_amdgcn_s_barrier();
    }
    if (w < 31) {
      // issue window w+1 into buf[(w+1)&1]; its readers finished at the
      // barrier above (they were window w-1)
      const uint4* gsrc = img + (size_t)(w + 1) * 4096 + wave * 64 + lane;
      char* dst = bb + ((w + 1) & 1) * 65536;
      #pragma unroll
      for (int i = 0; i < 8; ++i)
        gload_lds16(gsrc + i * 512, dst + (i * 512 + wave * 64) * 16);
    }

    const char* cbuf = bb + (w & 1) * 65536;

    // acc init: -nrm (scaled norm) at tile start (even windows)
    if ((w & 1) == 0) {
      #pragma unroll
      for (int cf = 0; cf < 8; ++cf) {
        int h = -nrm[tile * 512 + wc * 128 + cf * 16 + l15];
        #pragma unroll
        for (int rf = 0; rf < 4; ++rf) acc[rf][cf] = intx4{h, h, h, h};
      }
    }

    // two chunks per window
    #pragma unroll
    for (int half = 0; half < 2; ++half) {
      const int chunk = (w & 1) * 2 + half;
      intx4 a[4], b[8];
      #pragma unroll
      for (int rf = 0; rf < 4; ++rf) {
        int m = wgr * 64 + rf * 16 + l15;
        int by = (chunk * 64 + lgr * 16) ^ ((m & 15) << 4);
        a[rf] = *(const intx4*)(zb + m * 256 + by);
      }
      #pragma unroll
      for (int cf = 0; cf < 8; ++cf)
        b[cf] = *(const intx4*)(cbuf + half * 32768 + (wc * 512 + cf * 64 + lane) * 16);

      #pragma unroll
      for (int rf = 0; rf < 4; ++rf)
        #pragma unroll
        for (int cf = 0; cf < 8; ++cf)
          acc[rf][cf] = __builtin_amdgcn_mfma_i32_16x16x64_i8(a[rf], b[cf], acc[rf][cf], 0, 0, 0);
    }

    // tile epilogue on odd windows: fold 8 scores/row-slot into top-2
    // insert: k1' = max(k1,k); k2' = med3(k,k1,k2)  [== max(k2,min(k1,k))
    // given k1>=k2 invariant]
    if (w & 1) {
      const int jinvb = 8191 - (tile * 512 + wc * 128 + l15);
      #pragma unroll
      for (int rf = 0; rf < 4; ++rf)
        #pragma unroll
        for (int cf = 0; cf < 8; ++cf) {
          int jinv = jinvb - cf * 16;
          #pragma unroll
          for (int r = 0; r < 4; ++r) {
            int si = rf * 4 + r;
            int k = ((acc[rf][cf][r] >> 5) << 13) + jinv;
            int t1 = max(k1[si], k);
            int nk2;
            asm("v_med3_i32 %0, %1, %2, %3"
                : "=v"(nk2) : "v"(k), "v"(k1[si]), "v"(k2[si]));
            k2[si] = nk2;
            k1[si] = t1;
          }
        }
    }
  }

  // write candidates: [row][64 buckets] int2
  #pragma unroll
  for (int rf = 0; rf < 4; ++rf)
    #pragma unroll
    for (int r = 0; r < 4; ++r) {
      int row = brow + wgr * 64 + rf * 16 + lgr * 4 + r;
      int si = rf * 4 + r;
      cand[(size_t)row * 64 + wc * 16 + l15] = make_int2(k1[si], k2[si]);
    }
}

// ---------------- K5: exact fp64 refine (top-5) + outputs + loss partials ----
__global__ __launch_bounds__(512)
void k_refine(const float* __restrict__ z, const float* __restrict__ cbTf,
              const int2* __restrict__ cand, float* __restrict__ zq,
              float* __restrict__ oidx, double* __restrict__ parts) {
  __shared__ double lsum[8];
  int lane = threadIdx.x & 63, wave = threadIdx.x >> 6;
  int row = blockIdx.x * 8 + wave;

  float4 z4 = ((const float4*)(z + (size_t)row * DIMS))[lane];
  int2 kp = cand[(size_t)row * 64 + lane];
  int ka = kp.x, kb = kp.y;

  double bd = 1e300; int bj = -1; float4 bc = {0.f, 0.f, 0.f, 0.f};
  for (int s = 0; s < 5; ++s) {
    int km = max(ka, kb);
    #pragma unroll
    for (int m = 1; m < 64; m <<= 1) km = max(km, __shfl_xor(km, m, 64));
    int j = 8191 - (km & 8191);
    if (ka == km) ka = KMIN; else if (kb == km) kb = KMIN;

    float4 c4 = ((const float4*)(cbTf + (size_t)j * DIMS))[lane];
    double dx = (double)z4.x - (double)c4.x;
    double dy = (double)z4.y - (double)c4.y;
    double dzv = (double)z4.z - (double)c4.z;
    double dw = (double)z4.w - (double)c4.w;
    double d = dx * dx + dy * dy + dzv * dzv + dw * dw;
    #pragma unroll
    for (int m = 1; m < 64; m <<= 1) d += __shfl_xor(d, m, 64);

    bool bt = (d < bd) || (d == bd && j < bj);   // wave-uniform
    if (bt) { bd = d; bj = j; bc = c4; }
  }

  ((float4*)(zq + (size_t)row * DIMS))[lane] = bc;
  if (lane == 0) oidx[row] = (float)bj;

  double lx = (double)bc.x - (double)z4.x;
  double ly = (double)bc.y - (double)z4.y;
  double lz = (double)bc.z - (double)z4.z;
  double lw = (double)bc.w - (double)z4.w;
  double l = lx * lx + ly * ly + lz * lz + lw * lw;
  #pragma unroll
  for (int m = 1; m < 64; m <<= 1) l += __shfl_xor(l, m, 64);
  if (lane == 0) lsum[wave] = l;
  __syncthreads();
  if (threadIdx.x == 0) {
    double s = 0;
    for (int i = 0; i < 8; ++i) s += lsum[i];
    parts[blockIdx.x] = s;
  }
}

// ---------------- K6: loss finalize ----------------
__global__ void k_finish(const double* __restrict__ parts, float* __restrict__ out) {
  __shared__ double s[256];
  double a = 0;
  for (int i = threadIdx.x; i < 4096; i += 256) a += parts[i];
  s[threadIdx.x] = a;
  __syncthreads();
  for (int w = 128; w; w >>= 1) {
    if (threadIdx.x < w) s[threadIdx.x] += s[threadIdx.x + w];
    __syncthreads();
  }
  if (threadIdx.x == 0) out[0] = (float)(1.25 * s[0] / 8388608.0);
}

// ---------------- launch ----------------
extern "C" void kernel_launch(void* const* d_in, const int* in_sizes, int n_in,
                              void* d_out, int out_size, void* d_ws, size_t ws_size,
                              hipStream_t stream) {
  const float* zin = (const float*)d_in[0];
  const float* cb  = (const float*)d_in[1];
  float* out = (float*)d_out;

  char* w = (char*)d_ws;
  int*    nrm   = (int*)w;                                          // 32 KB
  float*  cbTf  = (float*)(w + 32768);                              // 8 MB
  char*   imgb  = w + 32768 + 8388608;                              // 2 MB
  int2*   cand  = (int2*)(w + 32768 + 8388608 + 2097152);           // 16 MB
  double* parts = (double*)(w + 32768 + 8388608 + 2097152 + 16777216); // 32 KB

  float* zq_out   = out;
  float* idx_out  = out + 8388608;
  float* loss_out = out + 8388608 + 32768;

  k_nrm<<<dim3(256), dim3(256), 0, stream>>>(cb, nrm);
  k_transpose<<<dim3(128, 4), dim3(256), 0, stream>>>(cb, cbTf);
  k_image<<<dim3(512), dim3(256), 0, stream>>>(cbTf, (uint4*)imgb);
  k_scan<<<dim3(256), dim3(512), 0, stream>>>(zin, nrm, (const uint4*)imgb, cand);
  k_refine<<<dim3(4096), dim3(512), 0, stream>>>(zin, cbTf, cand, zq_out, idx_out, parts);
  k_finish<<<dim3(1), dim3(256), 0, stream>>>(parts, loss_out);
}